// Round 1
// baseline (378.345 us; speedup 1.0000x reference)
//
#include <hip/hip_runtime.h>
#include <hip/hip_bf16.h>

#define D_MODEL 1024
#define NH 16
#define HD 64
#define SEQ 2048
#define NB 2

typedef __attribute__((ext_vector_type(8))) short sh8;
typedef __attribute__((ext_vector_type(4))) short sh4;
typedef __attribute__((ext_vector_type(4))) float fx4;

__device__ __forceinline__ short f2bf(float x) {
    union { float f; unsigned u; } v; v.f = x;
    unsigned r = (v.u + 0x7FFFu + ((v.u >> 16) & 1u)) >> 16;
    return (short)r;
}
__device__ __forceinline__ float bf2f(short b) {
    union { float f; unsigned u; } v; v.u = ((unsigned)(unsigned short)b) << 16;
    return v.f;
}

// ---------------- bias table: bt[h][delta+2047], delta = k - q ----------------
__global__ __launch_bounds__(256) void bias_kernel(const float* __restrict__ rel_emb,
                                                   float* __restrict__ bt) {
    int i = blockIdx.x * 256 + threadIdx.x;
    if (i >= NH * 4095) return;
    int h = i / 4095;
    int delta = (i % 4095) - 2047;
    int rb = delta > 0 ? 16 : 0;
    int ad = delta < 0 ? -delta : delta;
    int bidx;
    // integer thresholds reproducing f32: 8 + int(log(ad/8)/log(16)*8), clamped 15
    if (ad < 8) bidx = ad;
    else if (ad < 12) bidx = 8;
    else if (ad < 16) bidx = 9;
    else if (ad < 23) bidx = 10;
    else if (ad < 32) bidx = 11;
    else if (ad < 46) bidx = 12;
    else if (ad < 64) bidx = 13;
    else if (ad < 91) bidx = 14;
    else bidx = 15;
    bt[h * 4095 + (delta + 2047)] = rel_emb[(rb + bidx) * NH + h];
}

// ---------------- GEMM: C[m][n] = sum_k A[m][k] * B[n][k] --------------------
// SPLIT=1: bf16x3 (hi*hi + hi*lo + lo*hi). QKV=1: fused QKV epilogue.
template <int SPLIT, int QKV>
__global__ __launch_bounds__(256) void gemm_kernel(
    const float* __restrict__ A, const float* __restrict__ Bq,
    const float* __restrict__ Bk, const float* __restrict__ Bv,
    float* __restrict__ Oq, float* __restrict__ Ok, short* __restrict__ Ov,
    float* __restrict__ Oplain) {
    const int K = D_MODEL;
    __shared__ short Ah[128][40];
    __shared__ short Bh[128][40];
    __shared__ short Al[SPLIT ? 128 : 1][40];
    __shared__ short Bl[SPLIT ? 128 : 1][40];

    int t = threadIdx.x;
    int nb = blockIdx.x, mb = blockIdx.y;
    int lane = t & 63, w = t >> 6;
    int wr = w >> 1, wc = w & 1;
    int fr = lane & 15, fk = (lane >> 4) << 3;

    const float* Bsel = Bq;
    int nlocal = nb * 128;
    if (QKV) {
        int proj = (nb * 128) >> 10;
        Bsel = proj == 0 ? Bq : (proj == 1 ? Bk : Bv);
        nlocal = (nb * 128) & 1023;
    }

    fx4 acc[4][4];
#pragma unroll
    for (int i = 0; i < 4; ++i)
#pragma unroll
        for (int j = 0; j < 4; ++j) acc[i][j] = (fx4){0.f, 0.f, 0.f, 0.f};

    for (int kb = 0; kb < K; kb += 32) {
        __syncthreads();
#pragma unroll
        for (int i = 0; i < 4; ++i) {
            int idx = t + i * 256;
            int row = idx >> 3;
            int c4 = (idx & 7) << 2;
            float4 av = *(const float4*)(A + (size_t)(mb * 128 + row) * K + kb + c4);
            float4 bv = *(const float4*)(Bsel + (size_t)(nlocal + row) * K + kb + c4);
            const float* ap = (const float*)&av;
            const float* bp = (const float*)&bv;
            sh4 ahv, alv, bhv, blv;
#pragma unroll
            for (int j = 0; j < 4; ++j) {
                short hh = f2bf(ap[j]);
                ahv[j] = hh;
                if (SPLIT) alv[j] = f2bf(ap[j] - bf2f(hh));
                short hb = f2bf(bp[j]);
                bhv[j] = hb;
                if (SPLIT) blv[j] = f2bf(bp[j] - bf2f(hb));
            }
            *(sh4*)&Ah[row][c4] = ahv;
            *(sh4*)&Bh[row][c4] = bhv;
            if (SPLIT) {
                *(sh4*)&Al[row][c4] = alv;
                *(sh4*)&Bl[row][c4] = blv;
            }
        }
        __syncthreads();

        sh8 afh[4], afl[4], bfh[4], bfl[4];
#pragma unroll
        for (int mi = 0; mi < 4; ++mi) {
            afh[mi] = *(const sh8*)&Ah[wr * 64 + mi * 16 + fr][fk];
            if (SPLIT) afl[mi] = *(const sh8*)&Al[wr * 64 + mi * 16 + fr][fk];
        }
#pragma unroll
        for (int ni = 0; ni < 4; ++ni) {
            bfh[ni] = *(const sh8*)&Bh[wc * 64 + ni * 16 + fr][fk];
            if (SPLIT) bfl[ni] = *(const sh8*)&Bl[wc * 64 + ni * 16 + fr][fk];
        }
#pragma unroll
        for (int mi = 0; mi < 4; ++mi)
#pragma unroll
            for (int ni = 0; ni < 4; ++ni) {
                acc[mi][ni] = __builtin_amdgcn_mfma_f32_16x16x32_bf16(afh[mi], bfh[ni], acc[mi][ni], 0, 0, 0);
                if (SPLIT) {
                    acc[mi][ni] = __builtin_amdgcn_mfma_f32_16x16x32_bf16(afh[mi], bfl[ni], acc[mi][ni], 0, 0, 0);
                    acc[mi][ni] = __builtin_amdgcn_mfma_f32_16x16x32_bf16(afl[mi], bfh[ni], acc[mi][ni], 0, 0, 0);
                }
            }
    }

#pragma unroll
    for (int mi = 0; mi < 4; ++mi)
#pragma unroll
        for (int ni = 0; ni < 4; ++ni)
#pragma unroll
            for (int r = 0; r < 4; ++r) {
                int m = mb * 128 + wr * 64 + mi * 16 + ((lane >> 4) << 2) + r;
                int n = nb * 128 + wc * 64 + ni * 16 + fr;
                float val = acc[mi][ni][r];
                if (QKV) {
                    int proj = n >> 10, nn = n & 1023;
                    int h = nn >> 6, d = nn & 63;
                    int b = m >> 11, s = m & 2047;
                    size_t off = (((size_t)(b * NH + h)) * SEQ + s) * HD + d;
                    if (proj == 0) Oq[off] = val;
                    else if (proj == 1) Ok[off] = val;
                    else Ov[off] = f2bf(val);
                } else {
                    Oplain[(size_t)m * D_MODEL + n] = val;
                }
            }
}

// ---------------- flash attention: BQ=64 (4 waves x 16 rows), BK=64 ----------
__global__ __launch_bounds__(256) void attn_kernel(
    const float* __restrict__ Qf, const float* __restrict__ Kf,
    const short* __restrict__ Vb, const float* __restrict__ bias,
    float* __restrict__ ctx) {
    __shared__ short Kh[64][72];
    __shared__ short Kl[64][72];
    __shared__ short Vt[64][72];
    __shared__ short Pl[4][16][72];

    int t = threadIdx.x;
    int lane = t & 63, w = t >> 6;
    int fr = lane & 15, fk = (lane >> 4) << 3;
    int qt = blockIdx.x, h = blockIdx.y, b = blockIdx.z;
    int qbase = qt * 64;
    size_t bh = (size_t)(b * NH + h);

    // Q fragments (hi/lo) register-resident
    const float* qrow = Qf + (bh * SEQ + qbase + w * 16 + fr) * HD;
    sh8 qh[2], ql[2];
#pragma unroll
    for (int ks = 0; ks < 2; ++ks) {
        float vals[8];
        *(float4*)&vals[0] = *(const float4*)(qrow + ks * 32 + fk);
        *(float4*)&vals[4] = *(const float4*)(qrow + ks * 32 + fk + 4);
#pragma unroll
        for (int j = 0; j < 8; ++j) {
            short hh = f2bf(vals[j]);
            qh[ks][j] = hh;
            ql[ks][j] = f2bf(vals[j] - bf2f(hh));
        }
    }

    float mrow[4] = {-1e30f, -1e30f, -1e30f, -1e30f};
    float lrow[4] = {0.f, 0.f, 0.f, 0.f};
    fx4 o[4];
#pragma unroll
    for (int di = 0; di < 4; ++di) o[di] = (fx4){0.f, 0.f, 0.f, 0.f};

    const float* bt = bias + h * 4095 + 2047;
    const float* kptr = Kf + bh * SEQ * HD;
    const short* vptr = Vb + bh * SEQ * HD;
    int qrow_hi = (lane >> 4) << 2;

    for (int kt = 0; kt < SEQ / 64; ++kt) {
        __syncthreads();
        // stage K hi/lo
#pragma unroll
        for (int i = 0; i < 4; ++i) {
            int idx = t + i * 256;
            int row = idx >> 4;
            int c4 = (idx & 15) << 2;
            float4 kv = *(const float4*)(kptr + (size_t)(kt * 64 + row) * HD + c4);
            const float* kp = (const float*)&kv;
            sh4 khv, klv;
#pragma unroll
            for (int j = 0; j < 4; ++j) {
                short hh = f2bf(kp[j]);
                khv[j] = hh;
                klv[j] = f2bf(kp[j] - bf2f(hh));
            }
            *(sh4*)&Kh[row][c4] = khv;
            *(sh4*)&Kl[row][c4] = klv;
        }
        // stage V transposed
        {
            int key = t >> 2, dg = (t & 3) << 4;
            sh8 v0 = *(const sh8*)(vptr + (size_t)(kt * 64 + key) * HD + dg);
            sh8 v1 = *(const sh8*)(vptr + (size_t)(kt * 64 + key) * HD + dg + 8);
#pragma unroll
            for (int j = 0; j < 8; ++j) Vt[dg + j][key] = v0[j];
#pragma unroll
            for (int j = 0; j < 8; ++j) Vt[dg + 8 + j][key] = v1[j];
        }
        __syncthreads();

        // scores = Q K^T (bf16x3)
        fx4 sc[4];
#pragma unroll
        for (int ni = 0; ni < 4; ++ni) sc[ni] = (fx4){0.f, 0.f, 0.f, 0.f};
#pragma unroll
        for (int ks = 0; ks < 2; ++ks)
#pragma unroll
            for (int ni = 0; ni < 4; ++ni) {
                sh8 kh = *(const sh8*)&Kh[ni * 16 + fr][ks * 32 + fk];
                sh8 kl = *(const sh8*)&Kl[ni * 16 + fr][ks * 32 + fk];
                sc[ni] = __builtin_amdgcn_mfma_f32_16x16x32_bf16(qh[ks], kh, sc[ni], 0, 0, 0);
                sc[ni] = __builtin_amdgcn_mfma_f32_16x16x32_bf16(ql[ks], kh, sc[ni], 0, 0, 0);
                sc[ni] = __builtin_amdgcn_mfma_f32_16x16x32_bf16(qh[ks], kl, sc[ni], 0, 0, 0);
            }

        // bias + online softmax (fp32)
#pragma unroll
        for (int r = 0; r < 4; ++r) {
            int qg = qbase + w * 16 + qrow_hi + r;
            float mx = -1e30f;
#pragma unroll
            for (int ni = 0; ni < 4; ++ni) {
                int kg = kt * 64 + ni * 16 + fr;
                sc[ni][r] += bt[kg - qg];
                mx = fmaxf(mx, sc[ni][r]);
            }
#pragma unroll
            for (int off = 1; off < 16; off <<= 1) mx = fmaxf(mx, __shfl_xor(mx, off, 64));
            float mnew = fmaxf(mrow[r], mx);
            float scale = __expf(mrow[r] - mnew);
            float rs = 0.f;
#pragma unroll
            for (int ni = 0; ni < 4; ++ni) {
                float p = __expf(sc[ni][r] - mnew);
                sc[ni][r] = p;
                rs += p;
            }
#pragma unroll
            for (int off = 1; off < 16; off <<= 1) rs += __shfl_xor(rs, off, 64);
            mrow[r] = mnew;
            lrow[r] = lrow[r] * scale + rs;
#pragma unroll
            for (int di = 0; di < 4; ++di) o[di][r] *= scale;
        }

        // P -> LDS (per-wave), re-read as A-fragments
#pragma unroll
        for (int ni = 0; ni < 4; ++ni)
#pragma unroll
            for (int r = 0; r < 4; ++r)
                Pl[w][qrow_hi + r][ni * 16 + fr] = f2bf(sc[ni][r]);
        __syncthreads();
        sh8 pa0 = *(const sh8*)&Pl[w][fr][fk];
        sh8 pa1 = *(const sh8*)&Pl[w][fr][32 + fk];
#pragma unroll
        for (int di = 0; di < 4; ++di) {
            sh8 vb0 = *(const sh8*)&Vt[di * 16 + fr][fk];
            o[di] = __builtin_amdgcn_mfma_f32_16x16x32_bf16(pa0, vb0, o[di], 0, 0, 0);
            sh8 vb1 = *(const sh8*)&Vt[di * 16 + fr][32 + fk];
            o[di] = __builtin_amdgcn_mfma_f32_16x16x32_bf16(pa1, vb1, o[di], 0, 0, 0);
        }
    }

    // epilogue: ctx[b][q][h*64+d]
#pragma unroll
    for (int di = 0; di < 4; ++di)
#pragma unroll
        for (int r = 0; r < 4; ++r) {
            int q = qbase + w * 16 + qrow_hi + r;
            int d = di * 16 + fr;
            ctx[((size_t)b * SEQ + q) * D_MODEL + h * HD + d] = o[di][r] / lrow[r];
        }
}

extern "C" void kernel_launch(void* const* d_in, const int* in_sizes, int n_in,
                              void* d_out, int out_size, void* d_ws, size_t ws_size,
                              hipStream_t stream) {
    const float* hidden = (const float*)d_in[0];
    const float* Wq = (const float*)d_in[1];
    const float* Wk = (const float*)d_in[2];
    const float* Wv = (const float*)d_in[3];
    const float* Wo = (const float*)d_in[4];
    const float* rel = (const float*)d_in[5];
    float* out = (float*)d_out;

    const size_t NE = (size_t)NB * NH * SEQ * HD;  // 4,194,304
    char* ws = (char*)d_ws;
    float* Qf = (float*)ws;  ws += NE * 4;
    float* Kf = (float*)ws;  ws += NE * 4;
    short* Vb = (short*)ws;  ws += NE * 2;
    float* ctxb = (float*)ws; ws += NE * 4;
    float* bias = (float*)ws; ws += (size_t)NH * 4095 * 4;

    bias_kernel<<<dim3(256), dim3(256), 0, stream>>>(rel, bias);
    gemm_kernel<1, 1><<<dim3(24, 32), dim3(256), 0, stream>>>(
        hidden, Wq, Wk, Wv, Qf, Kf, Vb, nullptr);
    attn_kernel<<<dim3(32, 16, 2), dim3(256), 0, stream>>>(Qf, Kf, Vb, bias, ctxb);
    gemm_kernel<0, 0><<<dim3(8, 32), dim3(256), 0, stream>>>(
        ctxb, Wo, nullptr, nullptr, nullptr, nullptr, nullptr, out);
}

// Round 2
// 339.463 us; speedup vs baseline: 1.1145x; 1.1145x over previous
//
#include <hip/hip_runtime.h>
#include <hip/hip_bf16.h>

#define D_MODEL 1024
#define NH 16
#define HD 64
#define SEQ 2048
#define NB 2

typedef __attribute__((ext_vector_type(8))) short sh8;
typedef __attribute__((ext_vector_type(4))) short sh4;
typedef __attribute__((ext_vector_type(4))) float fx4;

__device__ __forceinline__ short f2bf(float x) {
    union { float f; unsigned u; } v; v.f = x;
    unsigned r = (v.u + 0x7FFFu + ((v.u >> 16) & 1u)) >> 16;
    return (short)r;
}
__device__ __forceinline__ float bf2f(short b) {
    union { float f; unsigned u; } v; v.u = ((unsigned)(unsigned short)b) << 16;
    return v.f;
}

// ---------------- bias table: bt[h][delta+2047], delta = k - q ----------------
__global__ __launch_bounds__(256) void bias_kernel(const float* __restrict__ rel_emb,
                                                   float* __restrict__ bt) {
    int i = blockIdx.x * 256 + threadIdx.x;
    if (i >= NH * 4095) return;
    int h = i / 4095;
    int delta = (i % 4095) - 2047;
    int rb = delta > 0 ? 16 : 0;
    int ad = delta < 0 ? -delta : delta;
    int bidx;
    if (ad < 8) bidx = ad;
    else if (ad < 12) bidx = 8;
    else if (ad < 16) bidx = 9;
    else if (ad < 23) bidx = 10;
    else if (ad < 32) bidx = 11;
    else if (ad < 46) bidx = 12;
    else if (ad < 64) bidx = 13;
    else if (ad < 91) bidx = 14;
    else bidx = 15;
    bt[h * 4095 + (delta + 2047)] = rel_emb[(rb + bidx) * NH + h];
}

// ---------------- presplit: fp32 -> (hi, lo) bf16, 4 elems/thread -------------
__global__ __launch_bounds__(256) void presplit_kernel(const float* __restrict__ src,
                                                       short* __restrict__ hi,
                                                       short* __restrict__ lo, int n4) {
    int idx = blockIdx.x * 256 + threadIdx.x;
    if (idx >= n4) return;
    float4 v = ((const float4*)src)[idx];
    const float* p = (const float*)&v;
    sh4 h, l;
#pragma unroll
    for (int j = 0; j < 4; ++j) {
        short hh = f2bf(p[j]);
        h[j] = hh;
        l[j] = f2bf(p[j] - bf2f(hh));
    }
    *(sh4*)&hi[(size_t)idx * 4] = h;
    *(sh4*)&lo[(size_t)idx * 4] = l;
}

// ---------------- QKV GEMM (bf16x3), epilogue writes split Q/K + V^T ----------
__global__ __launch_bounds__(256) void qkv_gemm(
    const short* __restrict__ Hh, const short* __restrict__ Hl,
    const float* __restrict__ Wq, const float* __restrict__ Wk, const float* __restrict__ Wv,
    short* __restrict__ Qh, short* __restrict__ Ql,
    short* __restrict__ Kh, short* __restrict__ Kl, short* __restrict__ Vt) {
    __shared__ short Ah[128][40];
    __shared__ short Al[128][40];
    __shared__ short Bh[128][40];
    __shared__ short Bl[128][40];

    int t = threadIdx.x;
    int nb = blockIdx.x, mb = blockIdx.y;
    int lane = t & 63, w = t >> 6;
    int wr = w >> 1, wc = w & 1;
    int fr = lane & 15, fk = (lane >> 4) << 3;
    int qrhi = (lane >> 4) << 2;

    int proj = (nb * 128) >> 10;
    int nlocal = (nb * 128) & 1023;
    const float* Wsel = proj == 0 ? Wq : (proj == 1 ? Wk : Wv);

    fx4 acc[4][4];
#pragma unroll
    for (int i = 0; i < 4; ++i)
#pragma unroll
        for (int j = 0; j < 4; ++j) acc[i][j] = (fx4){0.f, 0.f, 0.f, 0.f};

    for (int kb = 0; kb < D_MODEL; kb += 32) {
        __syncthreads();
        // A from pre-split bf16
#pragma unroll
        for (int i = 0; i < 2; ++i) {
            int idx = i * 256 + t;
            int row = idx >> 2, c8 = (idx & 3) << 3;
            *(sh8*)&Ah[row][c8] = *(const sh8*)&Hh[(size_t)(mb * 128 + row) * D_MODEL + kb + c8];
            *(sh8*)&Al[row][c8] = *(const sh8*)&Hl[(size_t)(mb * 128 + row) * D_MODEL + kb + c8];
        }
        // B from fp32 weights, convert hi/lo
#pragma unroll
        for (int i = 0; i < 4; ++i) {
            int idx = i * 256 + t;
            int row = idx >> 3, c4 = (idx & 7) << 2;
            float4 bv = *(const float4*)(Wsel + (size_t)(nlocal + row) * D_MODEL + kb + c4);
            const float* bp = (const float*)&bv;
            sh4 bh_, bl_;
#pragma unroll
            for (int j = 0; j < 4; ++j) {
                short hh = f2bf(bp[j]);
                bh_[j] = hh;
                bl_[j] = f2bf(bp[j] - bf2f(hh));
            }
            *(sh4*)&Bh[row][c4] = bh_;
            *(sh4*)&Bl[row][c4] = bl_;
        }
        __syncthreads();

        sh8 afh[4], afl[4], bfh[4], bfl[4];
#pragma unroll
        for (int mi = 0; mi < 4; ++mi) {
            afh[mi] = *(const sh8*)&Ah[wr * 64 + mi * 16 + fr][fk];
            afl[mi] = *(const sh8*)&Al[wr * 64 + mi * 16 + fr][fk];
        }
#pragma unroll
        for (int ni = 0; ni < 4; ++ni) {
            bfh[ni] = *(const sh8*)&Bh[wc * 64 + ni * 16 + fr][fk];
            bfl[ni] = *(const sh8*)&Bl[wc * 64 + ni * 16 + fr][fk];
        }
#pragma unroll
        for (int mi = 0; mi < 4; ++mi)
#pragma unroll
            for (int ni = 0; ni < 4; ++ni) {
                acc[mi][ni] = __builtin_amdgcn_mfma_f32_16x16x32_bf16(afh[mi], bfh[ni], acc[mi][ni], 0, 0, 0);
                acc[mi][ni] = __builtin_amdgcn_mfma_f32_16x16x32_bf16(afh[mi], bfl[ni], acc[mi][ni], 0, 0, 0);
                acc[mi][ni] = __builtin_amdgcn_mfma_f32_16x16x32_bf16(afl[mi], bfh[ni], acc[mi][ni], 0, 0, 0);
            }
    }

    // epilogue
#pragma unroll
    for (int mi = 0; mi < 4; ++mi)
#pragma unroll
        for (int ni = 0; ni < 4; ++ni)
#pragma unroll
            for (int r = 0; r < 4; ++r) {
                int m = mb * 128 + wr * 64 + mi * 16 + qrhi + r;
                int n = nb * 128 + wc * 64 + ni * 16 + fr;
                int nn = n & 1023;
                int h = nn >> 6, d = nn & 63;
                int b = m >> 11, s = m & 2047;
                size_t bh = (size_t)(b * NH + h);
                float val = acc[mi][ni][r];
                if (proj == 0) {
                    short hh = f2bf(val);
                    Qh[(bh * SEQ + s) * HD + d] = hh;
                    Ql[(bh * SEQ + s) * HD + d] = f2bf(val - bf2f(hh));
                } else if (proj == 1) {
                    short hh = f2bf(val);
                    Kh[(bh * SEQ + s) * HD + d] = hh;
                    Kl[(bh * SEQ + s) * HD + d] = f2bf(val - bf2f(hh));
                } else {
                    Vt[(bh * HD + d) * SEQ + s] = f2bf(val);
                }
            }
}

// ---------------- flash attention: BQ=128, 4 waves x 32 q-rows ---------------
__global__ __launch_bounds__(256) void attn_kernel(
    const short* __restrict__ Qhg, const short* __restrict__ Qlg,
    const short* __restrict__ Khg, const short* __restrict__ Klg,
    const short* __restrict__ Vtg, const float* __restrict__ bias,
    short* __restrict__ ctx) {
    __shared__ short Ks[64][72];
    __shared__ short Kls[64][72];
    __shared__ short Vs[64][72];
    __shared__ short Pl[4][32][72];
    __shared__ float Bt[192];

    int t = threadIdx.x;
    int lane = t & 63, w = t >> 6;
    int fr = lane & 15, fk = (lane >> 4) << 3;
    int qrhi = (lane >> 4) << 2;
    int qt = blockIdx.x, h = blockIdx.y, b = blockIdx.z;
    int qbase = qt * 128;
    size_t bh = (size_t)(b * NH + h);

    // Q fragments hi/lo, register-resident: 32 rows per wave (2 groups of 16)
    sh8 qh[2][2], ql[2][2];
#pragma unroll
    for (int qg = 0; qg < 2; ++qg)
#pragma unroll
        for (int ks = 0; ks < 2; ++ks) {
            int row = qbase + w * 32 + qg * 16 + fr;
            qh[qg][ks] = *(const sh8*)&Qhg[(bh * SEQ + row) * HD + ks * 32 + fk];
            ql[qg][ks] = *(const sh8*)&Qlg[(bh * SEQ + row) * HD + ks * 32 + fk];
        }

    float mrow[2][4], lrow[2][4];
    fx4 o[2][4];
#pragma unroll
    for (int qg = 0; qg < 2; ++qg) {
#pragma unroll
        for (int r = 0; r < 4; ++r) { mrow[qg][r] = -1e30f; lrow[qg][r] = 0.f; }
#pragma unroll
        for (int di = 0; di < 4; ++di) o[qg][di] = (fx4){0.f, 0.f, 0.f, 0.f};
    }

    const short* kbase = Khg + bh * SEQ * HD;
    const short* klbase = Klg + bh * SEQ * HD;
    const short* vbase = Vtg + bh * HD * SEQ;

    for (int kt = 0; kt < SEQ / 64; ++kt) {
        __syncthreads();
        // stage K hi/lo (row-major [key][d]) and V^T (row-major [d][key])
#pragma unroll
        for (int i = 0; i < 2; ++i) {
            int idx = i * 256 + t;
            int row = idx >> 3, c8 = (idx & 7) << 3;
            *(sh8*)&Ks[row][c8] = *(const sh8*)&kbase[(size_t)(kt * 64 + row) * HD + c8];
            *(sh8*)&Kls[row][c8] = *(const sh8*)&klbase[(size_t)(kt * 64 + row) * HD + c8];
            *(sh8*)&Vs[row][c8] = *(const sh8*)&vbase[(size_t)row * SEQ + kt * 64 + c8];
        }
        if (t < 191) Bt[t] = bias[h * 4095 + 2047 + (kt * 64 - qbase - 127) + t];
        __syncthreads();

        // scores = Q K^T (bf16x3)
        fx4 sc[2][4];
#pragma unroll
        for (int qg = 0; qg < 2; ++qg)
#pragma unroll
            for (int ni = 0; ni < 4; ++ni) sc[qg][ni] = (fx4){0.f, 0.f, 0.f, 0.f};
#pragma unroll
        for (int ks = 0; ks < 2; ++ks)
#pragma unroll
            for (int ni = 0; ni < 4; ++ni) {
                sh8 kf = *(const sh8*)&Ks[ni * 16 + fr][ks * 32 + fk];
                sh8 klf = *(const sh8*)&Kls[ni * 16 + fr][ks * 32 + fk];
#pragma unroll
                for (int qg = 0; qg < 2; ++qg) {
                    sc[qg][ni] = __builtin_amdgcn_mfma_f32_16x16x32_bf16(qh[qg][ks], kf, sc[qg][ni], 0, 0, 0);
                    sc[qg][ni] = __builtin_amdgcn_mfma_f32_16x16x32_bf16(ql[qg][ks], kf, sc[qg][ni], 0, 0, 0);
                    sc[qg][ni] = __builtin_amdgcn_mfma_f32_16x16x32_bf16(qh[qg][ks], klf, sc[qg][ni], 0, 0, 0);
                }
            }

        // bias + online softmax + P write (wave-private Pl, no barrier)
#pragma unroll
        for (int qg = 0; qg < 2; ++qg)
#pragma unroll
            for (int r = 0; r < 4; ++r) {
                int bidx0 = 127 + fr - (w * 32 + qg * 16 + qrhi + r);
                float mx = -1e30f;
#pragma unroll
                for (int ni = 0; ni < 4; ++ni) {
                    sc[qg][ni][r] += Bt[bidx0 + ni * 16];
                    mx = fmaxf(mx, sc[qg][ni][r]);
                }
#pragma unroll
                for (int off = 1; off < 16; off <<= 1) mx = fmaxf(mx, __shfl_xor(mx, off, 64));
                float mnew = fmaxf(mrow[qg][r], mx);
                float scale = __expf(mrow[qg][r] - mnew);
                float rs = 0.f;
#pragma unroll
                for (int ni = 0; ni < 4; ++ni) {
                    float p = __expf(sc[qg][ni][r] - mnew);
                    sc[qg][ni][r] = p;
                    rs += p;
                }
#pragma unroll
                for (int off = 1; off < 16; off <<= 1) rs += __shfl_xor(rs, off, 64);
                mrow[qg][r] = mnew;
                lrow[qg][r] = lrow[qg][r] * scale + rs;
#pragma unroll
                for (int di = 0; di < 4; ++di) o[qg][di][r] *= scale;
                int prow = qg * 16 + qrhi + r;
                int shft = ((prow >> 3) & 1) << 3;
#pragma unroll
                for (int ni = 0; ni < 4; ++ni)
                    Pl[w][prow][ni * 16 + fr + shft] = f2bf(sc[qg][ni][r]);
            }

        // PV
        sh8 pa0[2], pa1[2];
#pragma unroll
        for (int qg = 0; qg < 2; ++qg) {
            int prow = qg * 16 + fr;
            int shft = ((fr >> 3) & 1) << 3;
            pa0[qg] = *(const sh8*)&Pl[w][prow][fk + shft];
            pa1[qg] = *(const sh8*)&Pl[w][prow][32 + fk + shft];
        }
#pragma unroll
        for (int di = 0; di < 4; ++di) {
            sh8 vb0 = *(const sh8*)&Vs[di * 16 + fr][fk];
            sh8 vb1 = *(const sh8*)&Vs[di * 16 + fr][32 + fk];
#pragma unroll
            for (int qg = 0; qg < 2; ++qg) {
                o[qg][di] = __builtin_amdgcn_mfma_f32_16x16x32_bf16(pa0[qg], vb0, o[qg][di], 0, 0, 0);
                o[qg][di] = __builtin_amdgcn_mfma_f32_16x16x32_bf16(pa1[qg], vb1, o[qg][di], 0, 0, 0);
            }
        }
    }

    // epilogue: ctx[b][q][h*64+d] as bf16
#pragma unroll
    for (int qg = 0; qg < 2; ++qg)
#pragma unroll
        for (int di = 0; di < 4; ++di)
#pragma unroll
            for (int r = 0; r < 4; ++r) {
                int q = qbase + w * 32 + qg * 16 + qrhi + r;
                int d = di * 16 + fr;
                ctx[((size_t)b * SEQ + q) * D_MODEL + h * HD + d] =
                    f2bf(o[qg][di][r] / lrow[qg][r]);
            }
}

// ---------------- output projection: bf16 A x fp32 W (plain bf16) ------------
__global__ __launch_bounds__(256) void o_gemm(
    const short* __restrict__ Actx, const float* __restrict__ Wo,
    float* __restrict__ out) {
    __shared__ short Ah[128][40];
    __shared__ short Bh[128][40];

    int t = threadIdx.x;
    int nb = blockIdx.x, mb = blockIdx.y;
    int lane = t & 63, w = t >> 6;
    int wr = w >> 1, wc = w & 1;
    int fr = lane & 15, fk = (lane >> 4) << 3;
    int qrhi = (lane >> 4) << 2;

    fx4 acc[4][4];
#pragma unroll
    for (int i = 0; i < 4; ++i)
#pragma unroll
        for (int j = 0; j < 4; ++j) acc[i][j] = (fx4){0.f, 0.f, 0.f, 0.f};

    for (int kb = 0; kb < D_MODEL; kb += 32) {
        __syncthreads();
#pragma unroll
        for (int i = 0; i < 2; ++i) {
            int idx = i * 256 + t;
            int row = idx >> 2, c8 = (idx & 3) << 3;
            *(sh8*)&Ah[row][c8] = *(const sh8*)&Actx[(size_t)(mb * 128 + row) * D_MODEL + kb + c8];
        }
#pragma unroll
        for (int i = 0; i < 4; ++i) {
            int idx = i * 256 + t;
            int row = idx >> 3, c4 = (idx & 7) << 2;
            float4 bv = *(const float4*)(Wo + (size_t)(nb * 128 + row) * D_MODEL + kb + c4);
            const float* bp = (const float*)&bv;
            sh4 bh_;
#pragma unroll
            for (int j = 0; j < 4; ++j) bh_[j] = f2bf(bp[j]);
            *(sh4*)&Bh[row][c4] = bh_;
        }
        __syncthreads();

        sh8 af[4], bf[4];
#pragma unroll
        for (int mi = 0; mi < 4; ++mi) af[mi] = *(const sh8*)&Ah[wr * 64 + mi * 16 + fr][fk];
#pragma unroll
        for (int ni = 0; ni < 4; ++ni) bf[ni] = *(const sh8*)&Bh[wc * 64 + ni * 16 + fr][fk];
#pragma unroll
        for (int mi = 0; mi < 4; ++mi)
#pragma unroll
            for (int ni = 0; ni < 4; ++ni)
                acc[mi][ni] = __builtin_amdgcn_mfma_f32_16x16x32_bf16(af[mi], bf[ni], acc[mi][ni], 0, 0, 0);
    }

#pragma unroll
    for (int mi = 0; mi < 4; ++mi)
#pragma unroll
        for (int ni = 0; ni < 4; ++ni)
#pragma unroll
            for (int r = 0; r < 4; ++r) {
                int m = mb * 128 + wr * 64 + mi * 16 + qrhi + r;
                int n = nb * 128 + wc * 64 + ni * 16 + fr;
                out[(size_t)m * D_MODEL + n] = acc[mi][ni][r];
            }
}

extern "C" void kernel_launch(void* const* d_in, const int* in_sizes, int n_in,
                              void* d_out, int out_size, void* d_ws, size_t ws_size,
                              hipStream_t stream) {
    const float* hidden = (const float*)d_in[0];
    const float* Wq = (const float*)d_in[1];
    const float* Wk = (const float*)d_in[2];
    const float* Wv = (const float*)d_in[3];
    const float* Wo = (const float*)d_in[4];
    const float* rel = (const float*)d_in[5];
    float* out = (float*)d_out;

    const size_t NE = (size_t)NB * NH * SEQ * HD;  // 4,194,304
    char* ws = (char*)d_ws;
    short* Qh = (short*)(ws + 0 * NE * 2);
    short* Ql = (short*)(ws + 1 * NE * 2);
    short* Kh = (short*)(ws + 2 * NE * 2);
    short* Kl = (short*)(ws + 3 * NE * 2);
    short* Vt = (short*)(ws + 4 * NE * 2);
    short* Hh = (short*)(ws + 5 * NE * 2);
    short* Hl = (short*)(ws + 6 * NE * 2);
    short* ctxb = Hh;  // alias: Hh dead after qkv_gemm
    float* bias = (float*)(ws + 7 * NE * 2);

    bias_kernel<<<dim3(256), dim3(256), 0, stream>>>(rel, bias);
    presplit_kernel<<<dim3(4096), dim3(256), 0, stream>>>(hidden, Hh, Hl, 1048576);
    qkv_gemm<<<dim3(24, 32), dim3(256), 0, stream>>>(Hh, Hl, Wq, Wk, Wv, Qh, Ql, Kh, Kl, Vt);
    attn_kernel<<<dim3(16, 16, 2), dim3(256), 0, stream>>>(Qh, Ql, Kh, Kl, Vt, bias, ctxb);
    o_gemm<<<dim3(8, 32), dim3(256), 0, stream>>>(ctxb, Wo, out);
}

// Round 3
// 262.797 us; speedup vs baseline: 1.4397x; 1.2917x over previous
//
#include <hip/hip_runtime.h>
#include <hip/hip_bf16.h>

#define D_MODEL 1024
#define NH 16
#define HD 64
#define SEQ 2048
#define NB 2

typedef __attribute__((ext_vector_type(8))) short sh8;
typedef __attribute__((ext_vector_type(4))) short sh4;
typedef __attribute__((ext_vector_type(4))) float fx4;

__device__ __forceinline__ short f2bf(float x) {
    union { float f; unsigned u; } v; v.f = x;
    unsigned r = (v.u + 0x7FFFu + ((v.u >> 16) & 1u)) >> 16;
    return (short)r;
}
__device__ __forceinline__ float bf2f(short b) {
    union { float f; unsigned u; } v; v.u = ((unsigned)(unsigned short)b) << 16;
    return v.f;
}

// ---------------- bias table: bt[h][delta+2047], delta = k - q ----------------
__global__ __launch_bounds__(256) void bias_kernel(const float* __restrict__ rel_emb,
                                                   float* __restrict__ bt) {
    int i = blockIdx.x * 256 + threadIdx.x;
    if (i >= NH * 4095) return;
    int h = i / 4095;
    int delta = (i % 4095) - 2047;
    int rb = delta > 0 ? 16 : 0;
    int ad = delta < 0 ? -delta : delta;
    int bidx;
    if (ad < 8) bidx = ad;
    else if (ad < 12) bidx = 8;
    else if (ad < 16) bidx = 9;
    else if (ad < 23) bidx = 10;
    else if (ad < 32) bidx = 11;
    else if (ad < 46) bidx = 12;
    else if (ad < 64) bidx = 13;
    else if (ad < 91) bidx = 14;
    else bidx = 15;
    bt[h * 4095 + (delta + 2047)] = rel_emb[(rb + bidx) * NH + h];
}

// ---------------- presplit: fp32 -> (hi, lo) bf16, 4 elems/thread -------------
__global__ __launch_bounds__(256) void presplit_kernel(const float* __restrict__ src,
                                                       short* __restrict__ hi,
                                                       short* __restrict__ lo, int n4) {
    int idx = blockIdx.x * 256 + threadIdx.x;
    if (idx >= n4) return;
    float4 v = ((const float4*)src)[idx];
    const float* p = (const float*)&v;
    sh4 h, l;
#pragma unroll
    for (int j = 0; j < 4; ++j) {
        short hh = f2bf(p[j]);
        h[j] = hh;
        l[j] = f2bf(p[j] - bf2f(hh));
    }
    *(sh4*)&hi[(size_t)idx * 4] = h;
    *(sh4*)&lo[(size_t)idx * 4] = l;
}

// ---------------- cvt16: fp32 -> bf16 (hi only) ------------------------------
__global__ __launch_bounds__(256) void cvt16_kernel(const float* __restrict__ src,
                                                    short* __restrict__ hi, int n4) {
    int idx = blockIdx.x * 256 + threadIdx.x;
    if (idx >= n4) return;
    float4 v = ((const float4*)src)[idx];
    const float* p = (const float*)&v;
    sh4 h;
#pragma unroll
    for (int j = 0; j < 4; ++j) h[j] = f2bf(p[j]);
    *(sh4*)&hi[(size_t)idx * 4] = h;
}

// ---------------- QKV GEMM: A fp32->split in-kernel, B pre-split -------------
__global__ __launch_bounds__(256) void qkv_gemm(
    const float* __restrict__ H,
    const short* __restrict__ Wqh, const short* __restrict__ Wql,
    const short* __restrict__ Wkh, const short* __restrict__ Wkl,
    const short* __restrict__ Wvh, const short* __restrict__ Wvl,
    short* __restrict__ Qh, short* __restrict__ Ql,
    short* __restrict__ Kh, short* __restrict__ Kl, short* __restrict__ Vt) {
    __shared__ short Ah[128][40];
    __shared__ short Al[128][40];
    __shared__ short Bh[128][40];
    __shared__ short Bl[128][40];

    int t = threadIdx.x;
    int nb = blockIdx.x, mb = blockIdx.y;
    int lane = t & 63, w = t >> 6;
    int wr = w >> 1, wc = w & 1;
    int fr = lane & 15, fk = (lane >> 4) << 3;
    int qrhi = (lane >> 4) << 2;

    int proj = (nb * 128) >> 10;
    int nlocal = (nb * 128) & 1023;
    const short* Wh = proj == 0 ? Wqh : (proj == 1 ? Wkh : Wvh);
    const short* Wl = proj == 0 ? Wql : (proj == 1 ? Wkl : Wvl);

    fx4 acc[4][4];
#pragma unroll
    for (int i = 0; i < 4; ++i)
#pragma unroll
        for (int j = 0; j < 4; ++j) acc[i][j] = (fx4){0.f, 0.f, 0.f, 0.f};

    for (int kb = 0; kb < D_MODEL; kb += 32) {
        __syncthreads();
        // A from fp32 hidden, split hi/lo
#pragma unroll
        for (int i = 0; i < 4; ++i) {
            int idx = i * 256 + t;
            int row = idx >> 3, c4 = (idx & 7) << 2;
            float4 av = *(const float4*)(H + (size_t)(mb * 128 + row) * D_MODEL + kb + c4);
            const float* ap = (const float*)&av;
            sh4 ah_, al_;
#pragma unroll
            for (int j = 0; j < 4; ++j) {
                short hh = f2bf(ap[j]);
                ah_[j] = hh;
                al_[j] = f2bf(ap[j] - bf2f(hh));
            }
            *(sh4*)&Ah[row][c4] = ah_;
            *(sh4*)&Al[row][c4] = al_;
        }
        // B from pre-split bf16
#pragma unroll
        for (int i = 0; i < 2; ++i) {
            int idx = i * 256 + t;
            int row = idx >> 2, c8 = (idx & 3) << 3;
            *(sh8*)&Bh[row][c8] = *(const sh8*)&Wh[(size_t)(nlocal + row) * D_MODEL + kb + c8];
            *(sh8*)&Bl[row][c8] = *(const sh8*)&Wl[(size_t)(nlocal + row) * D_MODEL + kb + c8];
        }
        __syncthreads();

        sh8 afh[4], afl[4], bfh[4], bfl[4];
#pragma unroll
        for (int mi = 0; mi < 4; ++mi) {
            afh[mi] = *(const sh8*)&Ah[wr * 64 + mi * 16 + fr][fk];
            afl[mi] = *(const sh8*)&Al[wr * 64 + mi * 16 + fr][fk];
        }
#pragma unroll
        for (int ni = 0; ni < 4; ++ni) {
            bfh[ni] = *(const sh8*)&Bh[wc * 64 + ni * 16 + fr][fk];
            bfl[ni] = *(const sh8*)&Bl[wc * 64 + ni * 16 + fr][fk];
        }
#pragma unroll
        for (int mi = 0; mi < 4; ++mi)
#pragma unroll
            for (int ni = 0; ni < 4; ++ni) {
                acc[mi][ni] = __builtin_amdgcn_mfma_f32_16x16x32_bf16(afh[mi], bfh[ni], acc[mi][ni], 0, 0, 0);
                acc[mi][ni] = __builtin_amdgcn_mfma_f32_16x16x32_bf16(afh[mi], bfl[ni], acc[mi][ni], 0, 0, 0);
                acc[mi][ni] = __builtin_amdgcn_mfma_f32_16x16x32_bf16(afl[mi], bfh[ni], acc[mi][ni], 0, 0, 0);
            }
    }

    // epilogue: split Q/K hi/lo, V transposed bf16
#pragma unroll
    for (int mi = 0; mi < 4; ++mi)
#pragma unroll
        for (int ni = 0; ni < 4; ++ni)
#pragma unroll
            for (int r = 0; r < 4; ++r) {
                int m = mb * 128 + wr * 64 + mi * 16 + qrhi + r;
                int n = nb * 128 + wc * 64 + ni * 16 + fr;
                int nn = n & 1023;
                int h = nn >> 6, d = nn & 63;
                int b = m >> 11, s = m & 2047;
                size_t bh = (size_t)(b * NH + h);
                float val = acc[mi][ni][r];
                if (proj == 0) {
                    short hh = f2bf(val);
                    Qh[(bh * SEQ + s) * HD + d] = hh;
                    Ql[(bh * SEQ + s) * HD + d] = f2bf(val - bf2f(hh));
                } else if (proj == 1) {
                    short hh = f2bf(val);
                    Kh[(bh * SEQ + s) * HD + d] = hh;
                    Kl[(bh * SEQ + s) * HD + d] = f2bf(val - bf2f(hh));
                } else {
                    Vt[(bh * HD + d) * SEQ + s] = f2bf(val);
                }
            }
}

// swizzled LDS index (shorts): row-major [64][64], XOR bank swizzle
#define SW(row, scol) (((row) << 6) + ((scol) ^ (((row) & 7) << 3)))

// ---------------- flash attention v3: fixed-max softmax, T14 staging ---------
__global__ __launch_bounds__(256) void attn_kernel(
    const short* __restrict__ Qhg, const short* __restrict__ Qlg,
    const short* __restrict__ Khg, const short* __restrict__ Klg,
    const short* __restrict__ Vtg, const float* __restrict__ bias,
    short* __restrict__ ctx) {
    __shared__ short Ks[64 * 64];
    __shared__ short Kls[64 * 64];
    __shared__ short Vs[64 * 64];
    __shared__ short Pl[4][32][72];
    __shared__ float Bt[192];

    int t = threadIdx.x;
    int lane = t & 63, w = t >> 6;
    int fr = lane & 15, g = lane >> 4;
    int fk = g << 3;
    int qrhi = g << 2;
    int qt = blockIdx.x, h = blockIdx.y, b = blockIdx.z;
    int qbase = qt * 128;
    size_t bh = (size_t)(b * NH + h);

    // Q fragments hi/lo, register-resident: 32 rows per wave
    sh8 qh[2][2], ql[2][2];
#pragma unroll
    for (int qg = 0; qg < 2; ++qg)
#pragma unroll
        for (int ks = 0; ks < 2; ++ks) {
            int row = qbase + w * 32 + qg * 16 + fr;
            qh[qg][ks] = *(const sh8*)&Qhg[(bh * SEQ + row) * HD + ks * 32 + fk];
            ql[qg][ks] = *(const sh8*)&Qlg[(bh * SEQ + row) * HD + ks * 32 + fk];
        }

    float lrow[2][4];
    fx4 o[2][4];
#pragma unroll
    for (int qg = 0; qg < 2; ++qg) {
#pragma unroll
        for (int r = 0; r < 4; ++r) lrow[qg][r] = 0.f;
#pragma unroll
        for (int di = 0; di < 4; ++di) o[qg][di] = (fx4){0.f, 0.f, 0.f, 0.f};
    }

    const short* kbase = Khg + bh * SEQ * HD;
    const short* klbase = Klg + bh * SEQ * HD;
    const short* vbase = Vtg + bh * HD * SEQ;

    // T14 staging registers
    sh8 rK[2], rKl[2], rV[2];
    float rB = 0.f;

    auto issue = [&](int kt) {
#pragma unroll
        for (int i = 0; i < 2; ++i) {
            int idx = i * 256 + t;
            int row = idx >> 3, c8 = (idx & 7) << 3;
            rK[i] = *(const sh8*)&kbase[(size_t)(kt * 64 + row) * HD + c8];
            rKl[i] = *(const sh8*)&klbase[(size_t)(kt * 64 + row) * HD + c8];
            rV[i] = *(const sh8*)&vbase[(size_t)row * SEQ + kt * 64 + c8];
        }
        if (t < 191) rB = bias[h * 4095 + 2047 + (kt * 64 - qbase - 127) + t];
    };

    issue(0);

    for (int kt = 0; kt < SEQ / 64; ++kt) {
        // write phase: regs (tile kt) -> swizzled LDS
#pragma unroll
        for (int i = 0; i < 2; ++i) {
            int idx = i * 256 + t;
            int row = idx >> 3, scol = (idx & 7) << 3;
            *(sh8*)&Ks[SW(row, scol)] = rK[i];
            *(sh8*)&Kls[SW(row, scol)] = rKl[i];
            *(sh8*)&Vs[SW(row, scol)] = rV[i];
        }
        if (t < 191) Bt[t] = rB;
        __syncthreads();
        if (kt < SEQ / 64 - 1) issue(kt + 1);

        // scores = Q K^T (bf16x3)
        fx4 sc[2][4];
#pragma unroll
        for (int qg = 0; qg < 2; ++qg)
#pragma unroll
            for (int ni = 0; ni < 4; ++ni) sc[qg][ni] = (fx4){0.f, 0.f, 0.f, 0.f};
#pragma unroll
        for (int ks = 0; ks < 2; ++ks)
#pragma unroll
            for (int ni = 0; ni < 4; ++ni) {
                sh8 kf = *(const sh8*)&Ks[SW(ni * 16 + fr, ks * 32 + fk)];
                sh8 klf = *(const sh8*)&Kls[SW(ni * 16 + fr, ks * 32 + fk)];
#pragma unroll
                for (int qg = 0; qg < 2; ++qg) {
                    sc[qg][ni] = __builtin_amdgcn_mfma_f32_16x16x32_bf16(qh[qg][ks], kf, sc[qg][ni], 0, 0, 0);
                    sc[qg][ni] = __builtin_amdgcn_mfma_f32_16x16x32_bf16(ql[qg][ks], kf, sc[qg][ni], 0, 0, 0);
                    sc[qg][ni] = __builtin_amdgcn_mfma_f32_16x16x32_bf16(qh[qg][ks], klf, sc[qg][ni], 0, 0, 0);
                }
            }

        // fixed-max softmax: p = exp(s + bias - 40), lane-local l accumulation
#pragma unroll
        for (int qg = 0; qg < 2; ++qg)
#pragma unroll
            for (int r = 0; r < 4; ++r) {
                int bidx0 = 127 + fr - (w * 32 + qg * 16 + qrhi + r);
                float psum = 0.f;
#pragma unroll
                for (int ni = 0; ni < 4; ++ni) {
                    float p = __expf(sc[qg][ni][r] + Bt[bidx0 + ni * 16] - 40.0f);
                    sc[qg][ni][r] = p;
                    psum += p;
                }
                lrow[qg][r] += psum;
                int prow = qg * 16 + qrhi + r;
                int shft = ((prow >> 3) & 1) << 3;
#pragma unroll
                for (int ni = 0; ni < 4; ++ni)
                    Pl[w][prow][ni * 16 + fr + shft] = f2bf(sc[qg][ni][r]);
            }

        // PV
        sh8 pa0[2], pa1[2];
#pragma unroll
        for (int qg = 0; qg < 2; ++qg) {
            int prow = qg * 16 + fr;
            int shft = ((fr >> 3) & 1) << 3;
            pa0[qg] = *(const sh8*)&Pl[w][prow][fk + shft];
            pa1[qg] = *(const sh8*)&Pl[w][prow][32 + fk + shft];
        }
#pragma unroll
        for (int di = 0; di < 4; ++di) {
            sh8 vb0 = *(const sh8*)&Vs[SW(di * 16 + fr, fk)];
            sh8 vb1 = *(const sh8*)&Vs[SW(di * 16 + fr, 32 + fk)];
#pragma unroll
            for (int qg = 0; qg < 2; ++qg) {
                o[qg][di] = __builtin_amdgcn_mfma_f32_16x16x32_bf16(pa0[qg], vb0, o[qg][di], 0, 0, 0);
                o[qg][di] = __builtin_amdgcn_mfma_f32_16x16x32_bf16(pa1[qg], vb1, o[qg][di], 0, 0, 0);
            }
        }
        __syncthreads();
    }

    // final l reduction across the 16 lanes of each row group (once)
#pragma unroll
    for (int qg = 0; qg < 2; ++qg)
#pragma unroll
        for (int r = 0; r < 4; ++r) {
#pragma unroll
            for (int off = 1; off < 16; off <<= 1)
                lrow[qg][r] += __shfl_xor(lrow[qg][r], off, 64);
        }

    // epilogue: ctx[b][q][h*64+d] as bf16
#pragma unroll
    for (int qg = 0; qg < 2; ++qg)
#pragma unroll
        for (int di = 0; di < 4; ++di)
#pragma unroll
            for (int r = 0; r < 4; ++r) {
                int q = qbase + w * 32 + qg * 16 + qrhi + r;
                int d = di * 16 + fr;
                ctx[((size_t)b * SEQ + q) * D_MODEL + h * HD + d] =
                    f2bf(o[qg][di][r] / lrow[qg][r]);
            }
}

// ---------------- output projection: bf16 x bf16 -----------------------------
__global__ __launch_bounds__(256) void o_gemm(
    const short* __restrict__ Actx, const short* __restrict__ Woh,
    float* __restrict__ out) {
    __shared__ short Ah[128][40];
    __shared__ short Bh[128][40];

    int t = threadIdx.x;
    int nb = blockIdx.x, mb = blockIdx.y;
    int lane = t & 63, w = t >> 6;
    int wr = w >> 1, wc = w & 1;
    int fr = lane & 15, fk = (lane >> 4) << 3;
    int qrhi = (lane >> 4) << 2;

    fx4 acc[4][4];
#pragma unroll
    for (int i = 0; i < 4; ++i)
#pragma unroll
        for (int j = 0; j < 4; ++j) acc[i][j] = (fx4){0.f, 0.f, 0.f, 0.f};

    for (int kb = 0; kb < D_MODEL; kb += 32) {
        __syncthreads();
#pragma unroll
        for (int i = 0; i < 2; ++i) {
            int idx = i * 256 + t;
            int row = idx >> 2, c8 = (idx & 3) << 3;
            *(sh8*)&Ah[row][c8] = *(const sh8*)&Actx[(size_t)(mb * 128 + row) * D_MODEL + kb + c8];
            *(sh8*)&Bh[row][c8] = *(const sh8*)&Woh[(size_t)(nb * 128 + row) * D_MODEL + kb + c8];
        }
        __syncthreads();

        sh8 af[4], bf[4];
#pragma unroll
        for (int mi = 0; mi < 4; ++mi) af[mi] = *(const sh8*)&Ah[wr * 64 + mi * 16 + fr][fk];
#pragma unroll
        for (int ni = 0; ni < 4; ++ni) bf[ni] = *(const sh8*)&Bh[wc * 64 + ni * 16 + fr][fk];
#pragma unroll
        for (int mi = 0; mi < 4; ++mi)
#pragma unroll
            for (int ni = 0; ni < 4; ++ni)
                acc[mi][ni] = __builtin_amdgcn_mfma_f32_16x16x32_bf16(af[mi], bf[ni], acc[mi][ni], 0, 0, 0);
    }

#pragma unroll
    for (int mi = 0; mi < 4; ++mi)
#pragma unroll
        for (int ni = 0; ni < 4; ++ni)
#pragma unroll
            for (int r = 0; r < 4; ++r) {
                int m = mb * 128 + wr * 64 + mi * 16 + qrhi + r;
                int n = nb * 128 + wc * 64 + ni * 16 + fr;
                out[(size_t)m * D_MODEL + n] = acc[mi][ni][r];
            }
}

extern "C" void kernel_launch(void* const* d_in, const int* in_sizes, int n_in,
                              void* d_out, int out_size, void* d_ws, size_t ws_size,
                              hipStream_t stream) {
    const float* hidden = (const float*)d_in[0];
    const float* Wq = (const float*)d_in[1];
    const float* Wk = (const float*)d_in[2];
    const float* Wv = (const float*)d_in[3];
    const float* Wo = (const float*)d_in[4];
    const float* rel = (const float*)d_in[5];
    float* out = (float*)d_out;

    const size_t NE = (size_t)NB * NH * SEQ * HD;   // 4,194,304 (x2B = 8MB)
    const size_t WE = (size_t)D_MODEL * D_MODEL;    // 1,048,576 (x2B = 2MB)
    char* ws = (char*)d_ws;
    short* Qh = (short*)(ws + 0 * NE * 2);
    short* Ql = (short*)(ws + 1 * NE * 2);
    short* Kh = (short*)(ws + 2 * NE * 2);
    short* Kl = (short*)(ws + 3 * NE * 2);
    short* Vt = (short*)(ws + 4 * NE * 2);
    char* wsp = ws + 5 * NE * 2;                    // 40MB mark
    short* Wqh = (short*)(wsp + 0 * WE * 2);
    short* Wql = (short*)(wsp + 1 * WE * 2);
    short* Wkh = (short*)(wsp + 2 * WE * 2);
    short* Wkl = (short*)(wsp + 3 * WE * 2);
    short* Wvh = (short*)(wsp + 4 * WE * 2);
    short* Wvl = (short*)(wsp + 5 * WE * 2);
    short* Woh = (short*)(wsp + 6 * WE * 2);        // survives until o_gemm
    float* bias = (float*)(wsp + 7 * WE * 2);       // 54MB mark, 262KB
    short* ctxb = Wqh;  // alias: Wq/Wk splits dead after qkv_gemm (8MB region)

    bias_kernel<<<dim3(256), dim3(256), 0, stream>>>(rel, bias);
    presplit_kernel<<<dim3(1024), dim3(256), 0, stream>>>(Wq, Wqh, Wql, 262144);
    presplit_kernel<<<dim3(1024), dim3(256), 0, stream>>>(Wk, Wkh, Wkl, 262144);
    presplit_kernel<<<dim3(1024), dim3(256), 0, stream>>>(Wv, Wvh, Wvl, 262144);
    cvt16_kernel<<<dim3(1024), dim3(256), 0, stream>>>(Wo, Woh, 262144);
    qkv_gemm<<<dim3(24, 32), dim3(256), 0, stream>>>(
        hidden, Wqh, Wql, Wkh, Wkl, Wvh, Wvl, Qh, Ql, Kh, Kl, Vt);
    attn_kernel<<<dim3(16, 16, 2), dim3(256), 0, stream>>>(Qh, Ql, Kh, Kl, Vt, bias, ctxb);
    o_gemm<<<dim3(8, 32), dim3(256), 0, stream>>>(ctxb, Woh, out);
}

// Round 4
// 257.449 us; speedup vs baseline: 1.4696x; 1.0208x over previous
//
#include <hip/hip_runtime.h>
#include <hip/hip_bf16.h>

#define D_MODEL 1024
#define NH 16
#define HD 64
#define SEQ 2048
#define NB 2

typedef __attribute__((ext_vector_type(8))) short sh8;
typedef __attribute__((ext_vector_type(4))) short sh4;
typedef __attribute__((ext_vector_type(4))) float fx4;

__device__ __forceinline__ short f2bf(float x) {
    union { float f; unsigned u; } v; v.f = x;
    unsigned r = (v.u + 0x7FFFu + ((v.u >> 16) & 1u)) >> 16;
    return (short)r;
}
__device__ __forceinline__ float bf2f(short b) {
    union { float f; unsigned u; } v; v.u = ((unsigned)(unsigned short)b) << 16;
    return v.f;
}

// async global->LDS, 16B per lane. LDS dest must be linear (wave base + lane*16).
// CK-style addrspace casts via uintptr_t (LDS offset lives in low 32 bits).
__device__ __forceinline__ void gl_lds16(const short* g, short* l) {
    __builtin_amdgcn_global_load_lds(
        (const __attribute__((address_space(1))) void*)(uintptr_t)(const void*)g,
        (__attribute__((address_space(3))) void*)(uintptr_t)(void*)l, 16, 0, 0);
}

// ---------------- bias table: bt[h][delta+2047], delta = k - q ----------------
__global__ __launch_bounds__(256) void bias_kernel(const float* __restrict__ rel_emb,
                                                   float* __restrict__ bt) {
    int i = blockIdx.x * 256 + threadIdx.x;
    if (i >= NH * 4095) return;
    int h = i / 4095;
    int delta = (i % 4095) - 2047;
    int rb = delta > 0 ? 16 : 0;
    int ad = delta < 0 ? -delta : delta;
    int bidx;
    if (ad < 8) bidx = ad;
    else if (ad < 12) bidx = 8;
    else if (ad < 16) bidx = 9;
    else if (ad < 23) bidx = 10;
    else if (ad < 32) bidx = 11;
    else if (ad < 46) bidx = 12;
    else if (ad < 64) bidx = 13;
    else if (ad < 91) bidx = 14;
    else bidx = 15;
    bt[h * 4095 + (delta + 2047)] = rel_emb[(rb + bidx) * NH + h];
}

// ---------------- presplit: fp32 -> (hi, lo) bf16, 4 elems/thread -------------
__global__ __launch_bounds__(256) void presplit_kernel(const float* __restrict__ src,
                                                       short* __restrict__ hi,
                                                       short* __restrict__ lo, int n4) {
    int idx = blockIdx.x * 256 + threadIdx.x;
    if (idx >= n4) return;
    float4 v = ((const float4*)src)[idx];
    const float* p = (const float*)&v;
    sh4 h, l;
#pragma unroll
    for (int j = 0; j < 4; ++j) {
        short hh = f2bf(p[j]);
        h[j] = hh;
        l[j] = f2bf(p[j] - bf2f(hh));
    }
    *(sh4*)&hi[(size_t)idx * 4] = h;
    *(sh4*)&lo[(size_t)idx * 4] = l;
}

// ---------------- cvt16: fp32 -> bf16 (hi only) ------------------------------
__global__ __launch_bounds__(256) void cvt16_kernel(const float* __restrict__ src,
                                                    short* __restrict__ hi, int n4) {
    int idx = blockIdx.x * 256 + threadIdx.x;
    if (idx >= n4) return;
    float4 v = ((const float4*)src)[idx];
    const float* p = (const float*)&v;
    sh4 h;
#pragma unroll
    for (int j = 0; j < 4; ++j) h[j] = f2bf(p[j]);
    *(sh4*)&hi[(size_t)idx * 4] = h;
}

// ---------------- QKV GEMM v2: dbuf LDS, 1 barrier/K-step, counted vmcnt -----
// LDS invariant (both A and B): L[row][c] = G[row][c ^ (row&3)], c = 16B chunk.
__global__ __launch_bounds__(256) void qkv_gemm(
    const float* __restrict__ H,
    const short* __restrict__ Wqh, const short* __restrict__ Wql,
    const short* __restrict__ Wkh, const short* __restrict__ Wkl,
    const short* __restrict__ Wvh, const short* __restrict__ Wvl,
    short* __restrict__ Qh, short* __restrict__ Ql,
    short* __restrict__ Kh, short* __restrict__ Kl, short* __restrict__ Vt) {
    __shared__ short Ah[2][4096];
    __shared__ short Al[2][4096];
    __shared__ short Bh[2][4096];
    __shared__ short Bl[2][4096];

    int t = threadIdx.x;
    int lane = t & 63, w = t >> 6;
    int wr = w >> 1, wc = w & 1;
    int fr = lane & 15, g = lane >> 4;
    int qrhi = g << 2;

    // XCD-bijective swizzle: 768 blocks, 96/XCD contiguous -> 3 B-panels/XCD in L2
    int lin = blockIdx.y * 24 + blockIdx.x;
    int swz = (lin & 7) * 96 + (lin >> 3);
    int nb = swz % 24, mb = swz / 24;

    int proj = (nb * 128) >> 10;
    int nlocal = (nb * 128) & 1023;
    const short* Wh = proj == 0 ? Wqh : (proj == 1 ? Wkh : Wvh);
    const short* Wl = proj == 0 ? Wql : (proj == 1 ? Wkl : Wvl);

    fx4 acc[4][4];
#pragma unroll
    for (int i = 0; i < 4; ++i)
#pragma unroll
        for (int j = 0; j < 4; ++j) acc[i][j] = (fx4){0.f, 0.f, 0.f, 0.f};

    const float* Abase = H + (size_t)(mb * 128) * D_MODEL;
    int row0 = t >> 2, c0 = t & 3;

    float4 rA[2][2];
    auto issueA = [&](int kt) {
        int kb = kt * 32;
#pragma unroll
        for (int i = 0; i < 2; ++i) {
            const float* p = Abase + (size_t)(row0 + i * 64) * D_MODEL + kb + c0 * 8;
            rA[i][0] = *(const float4*)p;
            rA[i][1] = *(const float4*)(p + 4);
        }
    };
    auto writeA = [&](int buf) {
#pragma unroll
        for (int i = 0; i < 2; ++i) {
            int row = row0 + i * 64;
            int dst = (row << 5) + ((c0 ^ (row & 3)) << 3);
            const float* p0 = (const float*)&rA[i][0];
            const float* p1 = (const float*)&rA[i][1];
            sh8 hv, lv;
#pragma unroll
            for (int j = 0; j < 4; ++j) {
                short a = f2bf(p0[j]); hv[j] = a; lv[j] = f2bf(p0[j] - bf2f(a));
                short b2 = f2bf(p1[j]); hv[4 + j] = b2; lv[4 + j] = f2bf(p1[j] - bf2f(b2));
            }
            *(sh8*)&Ah[buf][dst] = hv;
            *(sh8*)&Al[buf][dst] = lv;
        }
    };
    auto stageB = [&](int kt, int buf) {
        int kb = kt * 32;
#pragma unroll
        for (int i = 0; i < 2; ++i) {
            int idx = i * 256 + t;
            int row = row0 + i * 64;
            int csw = ((idx & 3) ^ (row & 3)) << 3;
            const short* gh = Wh + (size_t)(nlocal + row) * D_MODEL + kb + csw;
            const short* gl = Wl + (size_t)(nlocal + row) * D_MODEL + kb + csw;
            gl_lds16(gh, &Bh[buf][(i * 256 + w * 64) * 8]);
            gl_lds16(gl, &Bl[buf][(i * 256 + w * 64) * 8]);
        }
    };
    auto compute = [&](int buf) {
        sh8 afh[4], afl[4], bfh[4], bfl[4];
#pragma unroll
        for (int mi = 0; mi < 4; ++mi) {
            int row = wr * 64 + mi * 16 + fr;
            int off = (row << 5) + ((g ^ (row & 3)) << 3);
            afh[mi] = *(const sh8*)&Ah[buf][off];
            afl[mi] = *(const sh8*)&Al[buf][off];
        }
#pragma unroll
        for (int ni = 0; ni < 4; ++ni) {
            int row = wc * 64 + ni * 16 + fr;
            int off = (row << 5) + ((g ^ (row & 3)) << 3);
            bfh[ni] = *(const sh8*)&Bh[buf][off];
            bfl[ni] = *(const sh8*)&Bl[buf][off];
        }
#pragma unroll
        for (int mi = 0; mi < 4; ++mi)
#pragma unroll
            for (int ni = 0; ni < 4; ++ni) {
                acc[mi][ni] = __builtin_amdgcn_mfma_f32_16x16x32_bf16(afh[mi], bfh[ni], acc[mi][ni], 0, 0, 0);
                acc[mi][ni] = __builtin_amdgcn_mfma_f32_16x16x32_bf16(afh[mi], bfl[ni], acc[mi][ni], 0, 0, 0);
                acc[mi][ni] = __builtin_amdgcn_mfma_f32_16x16x32_bf16(afl[mi], bfh[ni], acc[mi][ni], 0, 0, 0);
            }
    };

    // prologue
    issueA(0);
    stageB(0, 0);
    writeA(0);                              // reg-dep waits rA(0)
    __builtin_amdgcn_sched_barrier(0);
    issueA(1);                              // stays in flight across barrier
    asm volatile("s_waitcnt vmcnt(4) lgkmcnt(0)" ::: "memory");
    __builtin_amdgcn_s_barrier();

    int cur = 0;
#pragma unroll 1
    for (int kt = 0; kt < 31; ++kt) {
        stageB(kt + 1, cur ^ 1);            // 4 x global_load_lds
        writeA(cur ^ 1);                    // rA holds tile kt+1; cvt + ds_write
        __builtin_amdgcn_sched_barrier(0);  // keep issueA after the glds
        if (kt < 30) issueA(kt + 2);
        compute(cur);
        if (kt < 30)
            asm volatile("s_waitcnt vmcnt(4) lgkmcnt(0)" ::: "memory");
        else
            asm volatile("s_waitcnt vmcnt(0) lgkmcnt(0)" ::: "memory");
        __builtin_amdgcn_s_barrier();
        cur ^= 1;
    }
    compute(cur);

    // epilogue: split Q/K hi/lo, V transposed bf16
#pragma unroll
    for (int mi = 0; mi < 4; ++mi)
#pragma unroll
        for (int ni = 0; ni < 4; ++ni)
#pragma unroll
            for (int r = 0; r < 4; ++r) {
                int m = mb * 128 + wr * 64 + mi * 16 + qrhi + r;
                int n = nb * 128 + wc * 64 + ni * 16 + fr;
                int nn = n & 1023;
                int h = nn >> 6, d = nn & 63;
                int b = m >> 11, s = m & 2047;
                size_t bh = (size_t)(b * NH + h);
                float val = acc[mi][ni][r];
                if (proj == 0) {
                    short hh = f2bf(val);
                    Qh[(bh * SEQ + s) * HD + d] = hh;
                    Ql[(bh * SEQ + s) * HD + d] = f2bf(val - bf2f(hh));
                } else if (proj == 1) {
                    short hh = f2bf(val);
                    Kh[(bh * SEQ + s) * HD + d] = hh;
                    Kl[(bh * SEQ + s) * HD + d] = f2bf(val - bf2f(hh));
                } else {
                    Vt[(bh * HD + d) * SEQ + s] = f2bf(val);
                }
            }
}

// swizzled LDS index (shorts): row-major [64][64], XOR bank swizzle
#define SW(row, scol) (((row) << 6) + ((scol) ^ (((row) & 7) << 3)))

// ---------------- flash attention: fixed-max softmax, T14 staging ------------
__global__ __launch_bounds__(256) void attn_kernel(
    const short* __restrict__ Qhg, const short* __restrict__ Qlg,
    const short* __restrict__ Khg, const short* __restrict__ Klg,
    const short* __restrict__ Vtg, const float* __restrict__ bias,
    short* __restrict__ ctx) {
    __shared__ short Ks[64 * 64];
    __shared__ short Kls[64 * 64];
    __shared__ short Vs[64 * 64];
    __shared__ short Pl[4][32][72];
    __shared__ float Bt[192];

    int t = threadIdx.x;
    int lane = t & 63, w = t >> 6;
    int fr = lane & 15, g = lane >> 4;
    int fk = g << 3;
    int qrhi = g << 2;
    int qt = blockIdx.x, h = blockIdx.y, b = blockIdx.z;
    int qbase = qt * 128;
    size_t bh = (size_t)(b * NH + h);

    sh8 qh[2][2], ql[2][2];
#pragma unroll
    for (int qg = 0; qg < 2; ++qg)
#pragma unroll
        for (int ks = 0; ks < 2; ++ks) {
            int row = qbase + w * 32 + qg * 16 + fr;
            qh[qg][ks] = *(const sh8*)&Qhg[(bh * SEQ + row) * HD + ks * 32 + fk];
            ql[qg][ks] = *(const sh8*)&Qlg[(bh * SEQ + row) * HD + ks * 32 + fk];
        }

    float lrow[2][4];
    fx4 o[2][4];
#pragma unroll
    for (int qg = 0; qg < 2; ++qg) {
#pragma unroll
        for (int r = 0; r < 4; ++r) lrow[qg][r] = 0.f;
#pragma unroll
        for (int di = 0; di < 4; ++di) o[qg][di] = (fx4){0.f, 0.f, 0.f, 0.f};
    }

    const short* kbase = Khg + bh * SEQ * HD;
    const short* klbase = Klg + bh * SEQ * HD;
    const short* vbase = Vtg + bh * HD * SEQ;

    sh8 rK[2], rKl[2], rV[2];
    float rB = 0.f;

    auto issue = [&](int kt) {
#pragma unroll
        for (int i = 0; i < 2; ++i) {
            int idx = i * 256 + t;
            int row = idx >> 3, c8 = (idx & 7) << 3;
            rK[i] = *(const sh8*)&kbase[(size_t)(kt * 64 + row) * HD + c8];
            rKl[i] = *(const sh8*)&klbase[(size_t)(kt * 64 + row) * HD + c8];
            rV[i] = *(const sh8*)&vbase[(size_t)row * SEQ + kt * 64 + c8];
        }
        if (t < 191) rB = bias[h * 4095 + 2047 + (kt * 64 - qbase - 127) + t];
    };

    issue(0);

    for (int kt = 0; kt < SEQ / 64; ++kt) {
#pragma unroll
        for (int i = 0; i < 2; ++i) {
            int idx = i * 256 + t;
            int row = idx >> 3, scol = (idx & 7) << 3;
            *(sh8*)&Ks[SW(row, scol)] = rK[i];
            *(sh8*)&Kls[SW(row, scol)] = rKl[i];
            *(sh8*)&Vs[SW(row, scol)] = rV[i];
        }
        if (t < 191) Bt[t] = rB;
        __syncthreads();
        if (kt < SEQ / 64 - 1) issue(kt + 1);

        fx4 sc[2][4];
#pragma unroll
        for (int qg = 0; qg < 2; ++qg)
#pragma unroll
            for (int ni = 0; ni < 4; ++ni) sc[qg][ni] = (fx4){0.f, 0.f, 0.f, 0.f};
#pragma unroll
        for (int ks = 0; ks < 2; ++ks)
#pragma unroll
            for (int ni = 0; ni < 4; ++ni) {
                sh8 kf = *(const sh8*)&Ks[SW(ni * 16 + fr, ks * 32 + fk)];
                sh8 klf = *(const sh8*)&Kls[SW(ni * 16 + fr, ks * 32 + fk)];
#pragma unroll
                for (int qg = 0; qg < 2; ++qg) {
                    sc[qg][ni] = __builtin_amdgcn_mfma_f32_16x16x32_bf16(qh[qg][ks], kf, sc[qg][ni], 0, 0, 0);
                    sc[qg][ni] = __builtin_amdgcn_mfma_f32_16x16x32_bf16(ql[qg][ks], kf, sc[qg][ni], 0, 0, 0);
                    sc[qg][ni] = __builtin_amdgcn_mfma_f32_16x16x32_bf16(qh[qg][ks], klf, sc[qg][ni], 0, 0, 0);
                }
            }

#pragma unroll
        for (int qg = 0; qg < 2; ++qg)
#pragma unroll
            for (int r = 0; r < 4; ++r) {
                int bidx0 = 127 + fr - (w * 32 + qg * 16 + qrhi + r);
                float psum = 0.f;
#pragma unroll
                for (int ni = 0; ni < 4; ++ni) {
                    float p = __expf(sc[qg][ni][r] + Bt[bidx0 + ni * 16] - 40.0f);
                    sc[qg][ni][r] = p;
                    psum += p;
                }
                lrow[qg][r] += psum;
                int prow = qg * 16 + qrhi + r;
                int shft = ((prow >> 3) & 1) << 3;
#pragma unroll
                for (int ni = 0; ni < 4; ++ni)
                    Pl[w][prow][ni * 16 + fr + shft] = f2bf(sc[qg][ni][r]);
            }

        sh8 pa0[2], pa1[2];
#pragma unroll
        for (int qg = 0; qg < 2; ++qg) {
            int prow = qg * 16 + fr;
            int shft = ((fr >> 3) & 1) << 3;
            pa0[qg] = *(const sh8*)&Pl[w][prow][fk + shft];
            pa1[qg] = *(const sh8*)&Pl[w][prow][32 + fk + shft];
        }
#pragma unroll
        for (int di = 0; di < 4; ++di) {
            sh8 vb0 = *(const sh8*)&Vs[SW(di * 16 + fr, fk)];
            sh8 vb1 = *(const sh8*)&Vs[SW(di * 16 + fr, 32 + fk)];
#pragma unroll
            for (int qg = 0; qg < 2; ++qg) {
                o[qg][di] = __builtin_amdgcn_mfma_f32_16x16x32_bf16(pa0[qg], vb0, o[qg][di], 0, 0, 0);
                o[qg][di] = __builtin_amdgcn_mfma_f32_16x16x32_bf16(pa1[qg], vb1, o[qg][di], 0, 0, 0);
            }
        }
        __syncthreads();
    }

#pragma unroll
    for (int qg = 0; qg < 2; ++qg)
#pragma unroll
        for (int r = 0; r < 4; ++r) {
#pragma unroll
            for (int off = 1; off < 16; off <<= 1)
                lrow[qg][r] += __shfl_xor(lrow[qg][r], off, 64);
        }

#pragma unroll
    for (int qg = 0; qg < 2; ++qg)
#pragma unroll
        for (int di = 0; di < 4; ++di)
#pragma unroll
            for (int r = 0; r < 4; ++r) {
                int q = qbase + w * 32 + qg * 16 + qrhi + r;
                int d = di * 16 + fr;
                ctx[((size_t)b * SEQ + q) * D_MODEL + h * HD + d] =
                    f2bf(o[qg][di][r] / lrow[qg][r]);
            }
}

// ---------------- output projection v2: 64x128 tile, dbuf, gload_lds ---------
__global__ __launch_bounds__(256) void o_gemm(
    const short* __restrict__ Actx, const short* __restrict__ Woh,
    float* __restrict__ out) {
    __shared__ short Ab[2][2048];
    __shared__ short Bb[2][4096];

    int t = threadIdx.x;
    int lane = t & 63, w = t >> 6;
    int wr = w >> 1, wc = w & 1;
    int fr = lane & 15, g = lane >> 4;
    int qrhi = g << 2;

    int lin = blockIdx.y * 8 + blockIdx.x;      // 512 blocks
    int swz = (lin & 7) * 64 + (lin >> 3);
    int nb = swz & 7, mb = swz >> 3;            // nb<8, mb<64

    fx4 acc[2][4];
#pragma unroll
    for (int i = 0; i < 2; ++i)
#pragma unroll
        for (int j = 0; j < 4; ++j) acc[i][j] = (fx4){0.f, 0.f, 0.f, 0.f};

    int row0 = t >> 2, c0 = t & 3;

    auto stage = [&](int kt, int buf) {
        int kb = kt * 32;
        {   // A: 256 chunks, 1/thread
            int row = row0;
            int csw = (c0 ^ (row & 3)) << 3;
            gl_lds16(&Actx[(size_t)(mb * 64 + row) * D_MODEL + kb + csw],
                     &Ab[buf][(w * 64) * 8]);
        }
#pragma unroll
        for (int i = 0; i < 2; ++i) {   // B: 512 chunks, 2/thread
            int row = row0 + i * 64;
            int csw = (c0 ^ (row & 3)) << 3;
            gl_lds16(&Woh[(size_t)(nb * 128 + row) * D_MODEL + kb + csw],
                     &Bb[buf][(i * 256 + w * 64) * 8]);
        }
    };
    auto compute = [&](int buf) {
        sh8 af[2], bf[4];
#pragma unroll
        for (int mi = 0; mi < 2; ++mi) {
            int row = wr * 32 + mi * 16 + fr;
            af[mi] = *(const sh8*)&Ab[buf][(row << 5) + ((g ^ (row & 3)) << 3)];
        }
#pragma unroll
        for (int ni = 0; ni < 4; ++ni) {
            int row = wc * 64 + ni * 16 + fr;
            bf[ni] = *(const sh8*)&Bb[buf][(row << 5) + ((g ^ (row & 3)) << 3)];
        }
#pragma unroll
        for (int mi = 0; mi < 2; ++mi)
#pragma unroll
            for (int ni = 0; ni < 4; ++ni)
                acc[mi][ni] = __builtin_amdgcn_mfma_f32_16x16x32_bf16(af[mi], bf[ni], acc[mi][ni], 0, 0, 0);
    };

    stage(0, 0);
    asm volatile("s_waitcnt vmcnt(0)" ::: "memory");
    __builtin_amdgcn_s_barrier();

    int cur = 0;
#pragma unroll 1
    for (int kt = 0; kt < 31; ++kt) {
        stage(kt + 1, cur ^ 1);
        compute(cur);
        asm volatile("s_waitcnt vmcnt(0)" ::: "memory");
        __builtin_amdgcn_s_barrier();
        cur ^= 1;
    }
    compute(cur);

#pragma unroll
    for (int mi = 0; mi < 2; ++mi)
#pragma unroll
        for (int ni = 0; ni < 4; ++ni)
#pragma unroll
            for (int r = 0; r < 4; ++r) {
                int m = mb * 64 + wr * 32 + mi * 16 + qrhi + r;
                int n = nb * 128 + wc * 64 + ni * 16 + fr;
                out[(size_t)m * D_MODEL + n] = acc[mi][ni][r];
            }
}

extern "C" void kernel_launch(void* const* d_in, const int* in_sizes, int n_in,
                              void* d_out, int out_size, void* d_ws, size_t ws_size,
                              hipStream_t stream) {
    const float* hidden = (const float*)d_in[0];
    const float* Wq = (const float*)d_in[1];
    const float* Wk = (const float*)d_in[2];
    const float* Wv = (const float*)d_in[3];
    const float* Wo = (const float*)d_in[4];
    const float* rel = (const float*)d_in[5];
    float* out = (float*)d_out;

    const size_t NE = (size_t)NB * NH * SEQ * HD;   // 4,194,304 (x2B = 8MB)
    const size_t WE = (size_t)D_MODEL * D_MODEL;    // 1,048,576 (x2B = 2MB)
    char* ws = (char*)d_ws;
    short* Qh = (short*)(ws + 0 * NE * 2);
    short* Ql = (short*)(ws + 1 * NE * 2);
    short* Kh = (short*)(ws + 2 * NE * 2);
    short* Kl = (short*)(ws + 3 * NE * 2);
    short* Vt = (short*)(ws + 4 * NE * 2);
    char* wsp = ws + 5 * NE * 2;                    // 40MB mark
    short* Wqh = (short*)(wsp + 0 * WE * 2);
    short* Wql = (short*)(wsp + 1 * WE * 2);
    short* Wkh = (short*)(wsp + 2 * WE * 2);
    short* Wkl = (short*)(wsp + 3 * WE * 2);
    short* Wvh = (short*)(wsp + 4 * WE * 2);
    short* Wvl = (short*)(wsp + 5 * WE * 2);
    short* Woh = (short*)(wsp + 6 * WE * 2);        // survives until o_gemm
    float* bias = (float*)(wsp + 7 * WE * 2);       // 54MB mark, 262KB
    short* ctxb = Wqh;  // alias: Wq/Wk splits dead after qkv_gemm (8MB region)

    bias_kernel<<<dim3(256), dim3(256), 0, stream>>>(rel, bias);
    presplit_kernel<<<dim3(1024), dim3(256), 0, stream>>>(Wq, Wqh, Wql, 262144);
    presplit_kernel<<<dim3(1024), dim3(256), 0, stream>>>(Wk, Wkh, Wkl, 262144);
    presplit_kernel<<<dim3(1024), dim3(256), 0, stream>>>(Wv, Wvh, Wvl, 262144);
    cvt16_kernel<<<dim3(1024), dim3(256), 0, stream>>>(Wo, Woh, 262144);
    qkv_gemm<<<dim3(24, 32), dim3(256), 0, stream>>>(
        hidden, Wqh, Wql, Wkh, Wkl, Wvh, Wvl, Qh, Ql, Kh, Kl, Vt);
    attn_kernel<<<dim3(16, 16, 2), dim3(256), 0, stream>>>(Qh, Ql, Kh, Kl, Vt, bias, ctxb);
    o_gemm<<<dim3(8, 64), dim3(256), 0, stream>>>(ctxb, Woh, out);
}